// Round 9
// baseline (47.232 us; speedup 1.0000x reference)
//
#include <hip/hip_runtime.h>
#include <math.h>

#define NSAMP 524288              // 2^19 samples per channel
#define CHUNK 8                   // samples per thread
#define WGT 256                   // threads per workgroup
#define NWGC 256                  // workgroups per channel
#define TOTWG 512                 // total workgroups (regular launch, 2/CU)
#define HIDDEN 16
#define LS 33                     // LDS row stride (conflict-free)
#define NTAB 512                  // p(theta) lookup table size

__device__ __forceinline__ float fast_tanh(float x) {
    float e = __expf(2.0f * x);
    return (e - 1.0f) / (e + 1.0f);
}

// (Mo,do) = (Ma,da) ∘ (Mb,db): apply b first, then a
__device__ __forceinline__ void compose5(const float* Ma, const float* da,
                                         const float* Mb, const float* db,
                                         float* Mo, float* dout) {
#pragma unroll
    for (int r = 0; r < 5; ++r) {
#pragma unroll
        for (int c = 0; c < 5; ++c) {
            float acc = 0.0f;
#pragma unroll
            for (int k = 0; k < 5; ++k) acc = fmaf(Ma[r*5+k], Mb[k*5+c], acc);
            Mo[r*5+c] = acc;
        }
        float acc = da[r];
#pragma unroll
        for (int k = 0; k < 5; ++k) acc = fmaf(Ma[r*5+k], db[k], acc);
        dout[r] = acc;
    }
}

// relaxed agent-scope helpers (sc1 load/store through L3; NO cache flush)
__device__ __forceinline__ float ld_agent(const float* p) {
    return __hip_atomic_load(p, __ATOMIC_RELAXED, __HIP_MEMORY_SCOPE_AGENT);
}
__device__ __forceinline__ void st_agent(float* p, float v) {
    __hip_atomic_store(p, v, __ATOMIC_RELAXED, __HIP_MEMORY_SCOPE_AGENT);
}
__device__ __forceinline__ unsigned ldu_agent(const unsigned* p) {
    return __hip_atomic_load(p, __ATOMIC_RELAXED, __HIP_MEMORY_SCOPE_AGENT);
}
__device__ __forceinline__ void stu_agent(unsigned* p, unsigned v) {
    __hip_atomic_store(p, v, __ATOMIC_RELAXED, __HIP_MEMORY_SCOPE_AGENT);
}

// Blelloch scan over n=WGT records laid out at buf[row*LS + 0..29].
// After call: buf[t] = EXCLUSIVE prefix (identity at t=0).
// Caller must capture buf[WGT-1] (inclusive total) between upsweep and
// downsweep; this helper does it via the publish callback pattern below,
// so instead we inline the scan at both call sites.

__global__ void __launch_bounds__(WGT, 2) k_fused(
    const float* __restrict__ X,
    const float* __restrict__ rate01,
    const float* __restrict__ phoff01,
    const float* __restrict__ W1,
    const float* __restrict__ b1,
    const float* __restrict__ W2,
    const float* __restrict__ b2,
    const float* __restrict__ amp,
    const float* __restrict__ bias_,
    const float* __restrict__ depth_,
    const float* __restrict__ g1p,
    const float* __restrict__ prevph,
    float* __restrict__ OUT,
    float* __restrict__ REC,
    float* __restrict__ ES,
    unsigned int* __restrict__ FLG,
    unsigned int* __restrict__ FLG2)
{
    __shared__ float Tp[NTAB];        // p(theta) table
    __shared__ float sM[WGT * LS];    // per-block records -> exclusive prefixes
    __shared__ float aM[NWGC * LS];   // master aggregate scan buffer
    __shared__ float sES[8];

    const int t   = threadIdx.x;
    const int vid = blockIdx.x;       // all TOTWG blocks co-resident (2/CU)
    const int c   = vid >> 8;         // NWGC = 256
    const int wc  = vid & (NWGC - 1);

    // self-zero this WG's flags (stale 1s from a previous call).
    // Safe: any spin on FLG[vid] starts >=4us later (after phase B);
    // FLG2[vid] is only set by the master AFTER it consumed FLG[vid],
    // which this WG publishes after this zero (same-thread, same-addr order).
    if (t == 0) {
        stu_agent(&FLG[vid], 0u);
        stu_agent(&FLG2[vid], 0u);
    }

    const float two_pi = 6.28318530717958647692f;
    const float rate   = fmaf(rate01[0], 4.9f, 0.1f);
    const float w0rev  = rate / 44100.0f;                    // rev per sample
    const float dscale = depth_[0] * 0.5f;
    const float g1     = g1p[0];
    const float b2v    = b2[0];
    const float ampv   = amp[0];
    const float biasv  = bias_[0];

    // ============ Phase 0: build p(theta) table (2 entries/thread) =========
#pragma unroll
    for (int e = 0; e < NTAB / WGT; ++e) {
        int j = t + e * WGT;
        float lfo = ampv * __cosf((float)j * (two_pi / (float)NTAB));
        float m = b2v;
#pragma unroll
        for (int jj = 0; jj < HIDDEN; ++jj) {
            float h = fast_tanh(fmaf(lfo, W1[jj], b1[jj]));
            m = fmaf(h, W2[jj], m);
        }
        float dd = fmaf(dscale, 1.0f + m, biasv);
        float td = __tanf(dd);
        Tp[j] = fast_tanh((1.0f - td) / (1.0f + td));
    }
    __syncthreads();

    const int gblk = wc * WGT + t;    // this thread's block idx within channel
    const long base = (long)c * NSAMP + (long)gblk * CHUNK;
    const float phrev = prevph[0] * (1.0f / two_pi) + (c ? phoff01[0] : 0.0f);

    // ============ Phase A: per-sample coefficient via table lookup =========
    float pv[CHUNK];
#pragma unroll
    for (int k = 0; k < CHUNK; ++k) {
        float ph = fmaf(w0rev, (float)(gblk * CHUNK + k + 1), phrev);
        float u = (ph - floorf(ph)) * (float)NTAB;
        int i0 = ((int)u) & (NTAB - 1);
        float f = u - floorf(u);
        int i1 = (i0 + 1) & (NTAB - 1);
        float t0 = Tp[i0];
        pv[k] = fmaf(f, Tp[i1] - t0, t0);
    }

    // ========== Phase B: per-block transform (M 5x5, d 5) ==================
    float v[6][5];
#pragma unroll
    for (int j = 0; j < 6; ++j)
#pragma unroll
        for (int r = 0; r < 5; ++r) v[j][r] = (j == r) ? 1.0f : 0.0f;

    {
        const float4* Xv = (const float4*)(X + base);
#pragma unroll
        for (int q = 0; q < CHUNK / 4; ++q) {
            float4 x4 = Xv[q];
            float xa[4] = {x4.x, x4.y, x4.z, x4.w};
#pragma unroll
            for (int ii = 0; ii < 4; ++ii) {
                float pp = pv[q*4 + ii], xx = xa[ii];
#pragma unroll
                for (int j = 0; j < 6; ++j) {
                    float xin = (j == 5) ? xx : 0.0f;
                    float u0 = fmaf(g1, v[j][4], xin);
                    float y0 = fmaf(pp, u0 - v[j][1], v[j][0]);
                    float y1 = fmaf(pp, y0 - v[j][2], v[j][1]);
                    float y2 = fmaf(pp, y1 - v[j][3], v[j][2]);
                    float y3 = fmaf(pp, y2 - v[j][4], v[j][3]);
                    v[j][0] = u0; v[j][1] = y0; v[j][2] = y1; v[j][3] = y2; v[j][4] = y3;
                }
            }
        }
    }

#pragma unroll
    for (int j = 0; j < 5; ++j)
#pragma unroll
        for (int r = 0; r < 5; ++r) sM[t*LS + r*5 + j] = v[j][r];
#pragma unroll
    for (int r = 0; r < 5; ++r) sM[t*LS + 25 + r] = v[5][r];
    __syncthreads();

    // ========== Blelloch upsweep (255 composes total) ======================
    for (int d = 0; d < 8; ++d) {
        if (t < (WGT >> (d + 1))) {
            int r = ((t + 1) << (d + 1)) - 1;
            int l = r - (1 << d);
            float Mr[25], dr[5], Ml[25], dl[5], Mn[25], dn[5];
#pragma unroll
            for (int k = 0; k < 25; ++k) { Mr[k] = sM[r*LS + k]; Ml[k] = sM[l*LS + k]; }
#pragma unroll
            for (int k = 0; k < 5; ++k) { dr[k] = sM[r*LS + 25 + k]; dl[k] = sM[l*LS + 25 + k]; }
            compose5(Mr, dr, Ml, dl, Mn, dn);    // later ∘ earlier
#pragma unroll
            for (int k = 0; k < 25; ++k) sM[r*LS + k] = Mn[k];
#pragma unroll
            for (int k = 0; k < 5; ++k) sM[r*LS + 25 + k] = dn[k];
        }
        __syncthreads();
    }

    // ===== publish WG aggregate (row WGT-1 = inclusive total) ==============
    if (t < 30)
        st_agent(&REC[(long)vid * 32 + t], sM[(WGT-1)*LS + t]);
    __syncthreads();                  // wave0 vmcnt drained: stores complete
    if (t == 0) {
        asm volatile("" ::: "memory");
        stu_agent(&FLG[vid], 1u);
    }

    // root <- identity, then downsweep (255 composes)
    if (t < 30)
        sM[(WGT-1)*LS + t] = (t < 25) ? ((t % 6 == 0) ? 1.0f : 0.0f) : 0.0f;
    __syncthreads();

    for (int d = 7; d >= 0; --d) {
        if (t < (WGT >> (d + 1))) {
            int r = ((t + 1) << (d + 1)) - 1;
            int l = r - (1 << d);
            float Mr[25], dr[5], Ml[25], dl[5], Mn[25], dn[5];
#pragma unroll
            for (int k = 0; k < 25; ++k) { Mr[k] = sM[r*LS + k]; Ml[k] = sM[l*LS + k]; }
#pragma unroll
            for (int k = 0; k < 5; ++k) { dr[k] = sM[r*LS + 25 + k]; dl[k] = sM[l*LS + 25 + k]; }
            // x[l] = parent prefix; x[r] = left_subtree ∘ parent prefix
#pragma unroll
            for (int k = 0; k < 25; ++k) sM[l*LS + k] = Mr[k];
#pragma unroll
            for (int k = 0; k < 5; ++k) sM[l*LS + 25 + k] = dr[k];
            compose5(Ml, dl, Mr, dr, Mn, dn);
#pragma unroll
            for (int k = 0; k < 25; ++k) sM[r*LS + k] = Mn[k];
#pragma unroll
            for (int k = 0; k < 5; ++k) sM[r*LS + 25 + k] = dn[k];
        }
        __syncthreads();
    }
    // sM[t] now = EXCLUSIVE prefix of block t within this WG

    // ===== Phase C (master WGs, wc==0): scan channel aggregates once =======
    if (wc == 0) {
        const unsigned int* fp = &FLG[c * NWGC + t];
        while (ldu_agent(fp) == 0u) { __builtin_amdgcn_s_sleep(2); }
        asm volatile("" ::: "memory");
        {
            const float* rp = REC + (long)(c * NWGC + t) * 32;
            float r[30];
#pragma unroll
            for (int k = 0; k < 30; ++k) r[k] = ld_agent(&rp[k]);
#pragma unroll
            for (int k = 0; k < 30; ++k) aM[t*LS + k] = r[k];
        }
        __syncthreads();

        for (int d = 0; d < 8; ++d) {
            if (t < (NWGC >> (d + 1))) {
                int r = ((t + 1) << (d + 1)) - 1;
                int l = r - (1 << d);
                float Mr[25], dr[5], Ml[25], dl[5], Mn[25], dn[5];
#pragma unroll
                for (int k = 0; k < 25; ++k) { Mr[k] = aM[r*LS + k]; Ml[k] = aM[l*LS + k]; }
#pragma unroll
                for (int k = 0; k < 5; ++k) { dr[k] = aM[r*LS + 25 + k]; dl[k] = aM[l*LS + 25 + k]; }
                compose5(Mr, dr, Ml, dl, Mn, dn);
#pragma unroll
                for (int k = 0; k < 25; ++k) aM[r*LS + k] = Mn[k];
#pragma unroll
                for (int k = 0; k < 5; ++k) aM[r*LS + 25 + k] = dn[k];
            }
            __syncthreads();
        }
        if (t < 30)
            aM[(NWGC-1)*LS + t] = (t < 25) ? ((t % 6 == 0) ? 1.0f : 0.0f) : 0.0f;
        __syncthreads();
        for (int d = 7; d >= 0; --d) {
            if (t < (NWGC >> (d + 1))) {
                int r = ((t + 1) << (d + 1)) - 1;
                int l = r - (1 << d);
                float Mr[25], dr[5], Ml[25], dl[5], Mn[25], dn[5];
#pragma unroll
                for (int k = 0; k < 25; ++k) { Mr[k] = aM[r*LS + k]; Ml[k] = aM[l*LS + k]; }
#pragma unroll
                for (int k = 0; k < 5; ++k) { dr[k] = aM[r*LS + 25 + k]; dl[k] = aM[l*LS + 25 + k]; }
#pragma unroll
                for (int k = 0; k < 25; ++k) aM[l*LS + k] = Mr[k];
#pragma unroll
                for (int k = 0; k < 5; ++k) aM[l*LS + 25 + k] = dr[k];
                compose5(Ml, dl, Mr, dr, Mn, dn);
#pragma unroll
                for (int k = 0; k < 25; ++k) aM[r*LS + k] = Mn[k];
#pragma unroll
                for (int k = 0; k < 5; ++k) aM[r*LS + 25 + k] = dn[k];
            }
            __syncthreads();
        }
        // aM[t] = exclusive prefix of aggregate t; entry state = d-part
#pragma unroll
        for (int r = 0; r < 5; ++r)
            st_agent(&ES[(long)(c * NWGC + t) * 8 + r], aM[t*LS + 25 + r]);
        __syncthreads();              // drain vmcnt -> ES stores complete
        asm volatile("" ::: "memory");
        stu_agent(&FLG2[c * NWGC + t], 1u);
    }

    // ===== All WGs: wait for own entry state (one flag, 5 floats) ==========
    if (t == 0) {
        const unsigned int* fp = &FLG2[c * NWGC + wc];
        while (ldu_agent(fp) == 0u) { __builtin_amdgcn_s_sleep(2); }
        asm volatile("" ::: "memory");
    }
    __syncthreads();
    if (t < 5) sES[t] = ld_agent(&ES[(long)(c * NWGC + wc) * 8 + t]);
    __syncthreads();
    float sw[5];
#pragma unroll
    for (int r = 0; r < 5; ++r) sw[r] = sES[r];

    // ====== Phase D: entry state = sM[t] (exclusive prefix) applied to sw ==
    float s0, s1, s2, s3, s4;
    {
        float s[5];
#pragma unroll
        for (int r = 0; r < 5; ++r) {
            float acc = sM[t*LS + 25 + r];
#pragma unroll
            for (int j = 0; j < 5; ++j) acc = fmaf(sM[t*LS + r*5 + j], sw[j], acc);
            s[r] = acc;
        }
        s0 = s[0]; s1 = s[1]; s2 = s[2]; s3 = s[3]; s4 = s[4];
    }

    {
        const float4* Xv = (const float4*)(X + base);
        float4* Ov = (float4*)(OUT + base);
#pragma unroll
        for (int q = 0; q < CHUNK / 4; ++q) {
            float4 x4 = Xv[q];
            float xa[4] = {x4.x, x4.y, x4.z, x4.w};
            float oa[4];
#pragma unroll
            for (int ii = 0; ii < 4; ++ii) {
                float pp = pv[q*4 + ii], xx = xa[ii];
                float u0 = fmaf(g1, s4, xx);
                float y0 = fmaf(pp, u0 - s1, s0);
                float y1 = fmaf(pp, y0 - s2, s1);
                float y2 = fmaf(pp, y1 - s3, s2);
                float y3 = fmaf(pp, y2 - s4, s3);
                s0 = u0; s1 = y0; s2 = y1; s3 = y2; s4 = y3;
                oa[ii] = 0.5f * (xx + y3);
            }
            float4 o; o.x = oa[0]; o.y = oa[1]; o.z = oa[2]; o.w = oa[3];
            Ov[q] = o;
        }
    }
}

extern "C" void kernel_launch(void* const* d_in, const int* in_sizes, int n_in,
                              void* d_out, int out_size, void* d_ws, size_t ws_size,
                              hipStream_t stream) {
    const float* x     = (const float*)d_in[0];
    const float* rate  = (const float*)d_in[1];
    const float* phoff = (const float*)d_in[2];
    const float* W1    = (const float*)d_in[3];
    const float* b1    = (const float*)d_in[4];
    const float* W2    = (const float*)d_in[5];
    const float* b2    = (const float*)d_in[6];
    const float* amp   = (const float*)d_in[7];
    const float* bias_ = (const float*)d_in[8];
    const float* depth = (const float*)d_in[9];
    const float* g1    = (const float*)d_in[10];
    const float* pph   = (const float*)d_in[11];
    float* out = (float*)d_out;

    float* REC = (float*)d_ws;                          // TOTWG*32 f (64 KB)
    float* ES  = REC + (long)TOTWG * 32;                // TOTWG*8 f  (16 KB)
    unsigned int* FLG  = (unsigned int*)(ES + (long)TOTWG * 8);
    unsigned int* FLG2 = FLG + TOTWG;

    k_fused<<<dim3(TOTWG), dim3(WGT), 0, stream>>>(
        x, rate, phoff, W1, b1, W2, b2, amp, bias_, depth, g1, pph,
        out, REC, ES, FLG, FLG2);
}

// Round 10
// 28.634 us; speedup vs baseline: 1.6495x; 1.6495x over previous
//
#include <hip/hip_runtime.h>
#include <math.h>

#define NSAMP 524288              // 2^19 samples per channel
#define CHUNK 8                   // samples per thread
#define WGT 256                   // threads per workgroup (4 waves)
#define NWGC 256                  // workgroups per channel
#define TOTWG 512                 // total workgroups (regular launch, 2/CU)
#define HIDDEN 16
#define NTAB 512                  // p(theta) lookup table size

__device__ __forceinline__ float fast_tanh(float x) {
    float e = __expf(2.0f * x);
    return (e - 1.0f) / (e + 1.0f);
}

// (Mo,do) = (Ma,da) ∘ (Mb,db): apply b first, then a
__device__ __forceinline__ void compose5(const float* Ma, const float* da,
                                         const float* Mb, const float* db,
                                         float* Mo, float* dout) {
#pragma unroll
    for (int r = 0; r < 5; ++r) {
#pragma unroll
        for (int c = 0; c < 5; ++c) {
            float acc = 0.0f;
#pragma unroll
            for (int k = 0; k < 5; ++k) acc = fmaf(Ma[r*5+k], Mb[k*5+c], acc);
            Mo[r*5+c] = acc;
        }
        float acc = da[r];
#pragma unroll
        for (int k = 0; k < 5; ++k) acc = fmaf(Ma[r*5+k], db[k], acc);
        dout[r] = acc;
    }
}

// relaxed agent-scope helpers (sc1 load/store; NO cache maintenance)
__device__ __forceinline__ float ld_agent(const float* p) {
    return __hip_atomic_load(p, __ATOMIC_RELAXED, __HIP_MEMORY_SCOPE_AGENT);
}
__device__ __forceinline__ void st_agent(float* p, float v) {
    __hip_atomic_store(p, v, __ATOMIC_RELAXED, __HIP_MEMORY_SCOPE_AGENT);
}
__device__ __forceinline__ unsigned ldu_agent(const unsigned* p) {
    return __hip_atomic_load(p, __ATOMIC_RELAXED, __HIP_MEMORY_SCOPE_AGENT);
}
__device__ __forceinline__ void stu_agent(unsigned* p, unsigned v) {
    __hip_atomic_store(p, v, __ATOMIC_RELAXED, __HIP_MEMORY_SCOPE_AGENT);
}

// in-register inclusive scan across the 64 lanes of a wave (6 shfl steps)
__device__ __forceinline__ void wave_incl_scan(float* M, float* d, int l) {
#pragma unroll
    for (int off = 1; off < 64; off <<= 1) {
        float pM[25], pd[5];
#pragma unroll
        for (int k = 0; k < 25; ++k) pM[k] = __shfl_up(M[k], (unsigned)off);
#pragma unroll
        for (int k = 0; k < 5; ++k)  pd[k] = __shfl_up(d[k], (unsigned)off);
        if (l >= off) {
            float Mn[25], dn[5];
            compose5(M, d, pM, pd, Mn, dn);     // cur ∘ prev
#pragma unroll
            for (int k = 0; k < 25; ++k) M[k] = Mn[k];
#pragma unroll
            for (int k = 0; k < 5; ++k)  d[k] = dn[k];
        }
    }
}

// exclusive prefix of the wave aggregates in LDS: P = W_{w-1} ∘ ... ∘ W_0
__device__ __forceinline__ void wave_prefix(const float wAp[][33], int w,
                                            float* PM, float* Pd) {
#pragma unroll
    for (int k = 0; k < 25; ++k) PM[k] = (k % 6 == 0) ? 1.0f : 0.0f;
#pragma unroll
    for (int k = 0; k < 5; ++k)  Pd[k] = 0.0f;
    for (int j = 0; j < w; ++j) {              // wave-uniform bound (0..3)
        float Wm[25], Wd[5], Mn[25], dn[5];
#pragma unroll
        for (int k = 0; k < 25; ++k) Wm[k] = wAp[j][k];       // LDS broadcast
#pragma unroll
        for (int k = 0; k < 5; ++k)  Wd[k] = wAp[j][25 + k];
        compose5(Wm, Wd, PM, Pd, Mn, dn);
#pragma unroll
        for (int k = 0; k < 25; ++k) PM[k] = Mn[k];
#pragma unroll
        for (int k = 0; k < 5; ++k)  Pd[k] = dn[k];
    }
}

__global__ void __launch_bounds__(WGT, 2) k_fused(
    const float* __restrict__ X,
    const float* __restrict__ rate01,
    const float* __restrict__ phoff01,
    const float* __restrict__ W1,
    const float* __restrict__ b1,
    const float* __restrict__ W2,
    const float* __restrict__ b2,
    const float* __restrict__ amp,
    const float* __restrict__ bias_,
    const float* __restrict__ depth_,
    const float* __restrict__ g1p,
    const float* __restrict__ prevph,
    float* __restrict__ OUT,
    float* __restrict__ RECT,     // transposed: RECT[k*TOTWG + vid], k<30
    float* __restrict__ EST,      // transposed: EST[r*TOTWG + vid], r<5
    unsigned int* __restrict__ FLG,
    unsigned int* __restrict__ FLG2)
{
    __shared__ float Tp[NTAB];
    __shared__ float wA[4][33];   // per-wave aggregates (30 used, pad to 33)

    const int t   = threadIdx.x;
    const int vid = blockIdx.x;
    const int c   = vid >> 8;           // NWGC = 256
    const int wc  = vid & (NWGC - 1);
    const int w   = t >> 6;             // wave id (0..3)
    const int l   = t & 63;             // lane id

    // self-zero this WG's flags (stale 1s from a previous replay are benign-
    // identical data; zeroing is required for the first call / poisoned ws)
    if (t == 0) { stu_agent(&FLG[vid], 0u); stu_agent(&FLG2[vid], 0u); }

    const float two_pi = 6.28318530717958647692f;
    const float rate   = fmaf(rate01[0], 4.9f, 0.1f);
    const float w0rev  = rate / 44100.0f;                    // rev per sample
    const float dscale = depth_[0] * 0.5f;
    const float g1     = g1p[0];
    const float b2v    = b2[0];
    const float ampv   = amp[0];
    const float biasv  = bias_[0];

    // ============ Phase 0: build p(theta) table (2 entries/thread) =========
#pragma unroll
    for (int e = 0; e < NTAB / WGT; ++e) {
        int j = t + e * WGT;
        float lfo = ampv * __cosf((float)j * (two_pi / (float)NTAB));
        float m = b2v;
#pragma unroll
        for (int jj = 0; jj < HIDDEN; ++jj) {
            float h = fast_tanh(fmaf(lfo, W1[jj], b1[jj]));
            m = fmaf(h, W2[jj], m);
        }
        float dd = fmaf(dscale, 1.0f + m, biasv);
        float td = __tanf(dd);
        Tp[j] = fast_tanh((1.0f - td) / (1.0f + td));
    }
    __syncthreads();

    const int gblk = wc * WGT + t;      // block idx within channel
    const long base = (long)c * NSAMP + (long)gblk * CHUNK;
    const float phrev = prevph[0] * (1.0f / two_pi) + (c ? phoff01[0] : 0.0f);

    // ============ Phase A: per-sample coefficient via table lookup =========
    float pv[CHUNK];
#pragma unroll
    for (int k = 0; k < CHUNK; ++k) {
        float ph = fmaf(w0rev, (float)(gblk * CHUNK + k + 1), phrev);
        float u = (ph - floorf(ph)) * (float)NTAB;
        int i0 = ((int)u) & (NTAB - 1);
        float f = u - floorf(u);
        int i1 = (i0 + 1) & (NTAB - 1);
        float t0 = Tp[i0];
        pv[k] = fmaf(f, Tp[i1] - t0, t0);
    }

    // ========== Phase B: per-block transform (M 5x5, d 5) ==================
    float v[6][5];
#pragma unroll
    for (int j = 0; j < 6; ++j)
#pragma unroll
        for (int r = 0; r < 5; ++r) v[j][r] = (j == r) ? 1.0f : 0.0f;

    {
        const float4* Xv = (const float4*)(X + base);
#pragma unroll
        for (int q = 0; q < CHUNK / 4; ++q) {
            float4 x4 = Xv[q];
            float xa[4] = {x4.x, x4.y, x4.z, x4.w};
#pragma unroll
            for (int ii = 0; ii < 4; ++ii) {
                float pp = pv[q*4 + ii], xx = xa[ii];
#pragma unroll
                for (int j = 0; j < 6; ++j) {
                    float xin = (j == 5) ? xx : 0.0f;
                    float u0 = fmaf(g1, v[j][4], xin);
                    float y0 = fmaf(pp, u0 - v[j][1], v[j][0]);
                    float y1 = fmaf(pp, y0 - v[j][2], v[j][1]);
                    float y2 = fmaf(pp, y1 - v[j][3], v[j][2]);
                    float y3 = fmaf(pp, y2 - v[j][4], v[j][3]);
                    v[j][0] = u0; v[j][1] = y0; v[j][2] = y1; v[j][3] = y2; v[j][4] = y3;
                }
            }
        }
    }

    float M[25], d[5];
#pragma unroll
    for (int j = 0; j < 5; ++j)
#pragma unroll
        for (int r = 0; r < 5; ++r) M[r*5+j] = v[j][r];
#pragma unroll
    for (int r = 0; r < 5; ++r) d[r] = v[5][r];

    // ========== intra-wave inclusive scan (registers + shuffles) ===========
    wave_incl_scan(M, d, l);

    if (l == 63) {
#pragma unroll
        for (int k = 0; k < 25; ++k) wA[w][k] = M[k];
#pragma unroll
        for (int k = 0; k < 5; ++k)  wA[w][25 + k] = d[k];
    }
    __syncthreads();

    float PM[25], Pd[5];                // exclusive wave prefix for my wave
    wave_prefix(wA, w, PM, Pd);

    // ===== publish WG total = W3 ∘ P3 (thread 255), transposed layout ======
    if (t == WGT - 1) {
        float Tm[25], Td[5];
        compose5(M, d, PM, Pd, Tm, Td);
#pragma unroll
        for (int k = 0; k < 25; ++k) st_agent(&RECT[k*TOTWG + vid], Tm[k]);
#pragma unroll
        for (int k = 0; k < 5; ++k)  st_agent(&RECT[(25+k)*TOTWG + vid], Td[k]);
    }
    __syncthreads();                    // drains t255's stores (vmcnt 0)
    if (t == 0) {
        asm volatile("" ::: "memory");
        stu_agent(&FLG[vid], 1u);
    }

    // ===== Phase C (master WGs, wc==0): scan 256 channel aggregates ========
    if (wc == 0) {
        const unsigned int* fp = &FLG[c * NWGC + t];
        while (ldu_agent(fp) == 0u) { __builtin_amdgcn_s_sleep(2); }
        asm volatile("" ::: "memory");
        float aM[25], ad[5];
#pragma unroll
        for (int k = 0; k < 25; ++k)    // coalesced across t
            aM[k] = ld_agent(&RECT[k*TOTWG + c*NWGC + t]);
#pragma unroll
        for (int k = 0; k < 5; ++k)
            ad[k] = ld_agent(&RECT[(25+k)*TOTWG + c*NWGC + t]);

        wave_incl_scan(aM, ad, l);
        if (l == 63) {                  // wA safe to reuse: all threads past
#pragma unroll                          // the pre-flag barrier above
            for (int k = 0; k < 25; ++k) wA[w][k] = aM[k];
#pragma unroll
            for (int k = 0; k < 5; ++k)  wA[w][25 + k] = ad[k];
        }
        __syncthreads();
        float aPM[25], aPd[5];
        wave_prefix(wA, w, aPM, aPd);

        // ES[t] = (exclusive prefix of aggregates)(0) = E_l( P_w(0)=aPd )
        float es[5];
#pragma unroll
        for (int r = 0; r < 5; ++r) {
            float acc = __shfl_up(ad[r], 1u);
#pragma unroll
            for (int j = 0; j < 5; ++j)
                acc = fmaf(__shfl_up(aM[r*5+j], 1u), aPd[j], acc);
            es[r] = (l == 0) ? aPd[r] : acc;
        }
#pragma unroll
        for (int r = 0; r < 5; ++r)     // coalesced across t
            st_agent(&EST[r*TOTWG + c*NWGC + t], es[r]);
        __syncthreads();                // drain each thread's ES stores
        asm volatile("" ::: "memory");
        stu_agent(&FLG2[c * NWGC + t], 1u);
    }

    // ===== all WGs: obtain entry state sw (no barriers; per-wave spin) =====
    float sw[5];
    if (wc != 0) {
        const unsigned int* fp = &FLG2[vid];
        while (ldu_agent(fp) == 0u) { __builtin_amdgcn_s_sleep(2); }
        asm volatile("" ::: "memory");
#pragma unroll
        for (int r = 0; r < 5; ++r)     // same addr all lanes -> broadcast
            sw[r] = ld_agent(&EST[r*TOTWG + vid]);
    } else {
#pragma unroll
        for (int r = 0; r < 5; ++r) sw[r] = 0.0f;
    }

    // ====== Phase D: s = E_l( P_w( sw ) ), then run recursion ==============
    float s1[5];
#pragma unroll
    for (int r = 0; r < 5; ++r) {
        float acc = Pd[r];
#pragma unroll
        for (int j = 0; j < 5; ++j) acc = fmaf(PM[r*5+j], sw[j], acc);
        s1[r] = acc;
    }
    float s0, s1r, s2, s3, s4;
    {
        float s[5];
#pragma unroll
        for (int r = 0; r < 5; ++r) {
            float acc = __shfl_up(d[r], 1u);
#pragma unroll
            for (int j = 0; j < 5; ++j)
                acc = fmaf(__shfl_up(M[r*5+j], 1u), s1[j], acc);
            s[r] = (l == 0) ? s1[r] : acc;
        }
        s0 = s[0]; s1r = s[1]; s2 = s[2]; s3 = s[3]; s4 = s[4];
    }

    {
        const float4* Xv = (const float4*)(X + base);
        float4* Ov = (float4*)(OUT + base);
#pragma unroll
        for (int q = 0; q < CHUNK / 4; ++q) {
            float4 x4 = Xv[q];
            float xa[4] = {x4.x, x4.y, x4.z, x4.w};
            float oa[4];
#pragma unroll
            for (int ii = 0; ii < 4; ++ii) {
                float pp = pv[q*4 + ii], xx = xa[ii];
                float u0 = fmaf(g1, s4, xx);
                float y0 = fmaf(pp, u0 - s1r, s0);
                float y1 = fmaf(pp, y0 - s2, s1r);
                float y2 = fmaf(pp, y1 - s3, s2);
                float y3 = fmaf(pp, y2 - s4, s3);
                s0 = u0; s1r = y0; s2 = y1; s3 = y2; s4 = y3;
                oa[ii] = 0.5f * (xx + y3);
            }
            float4 o; o.x = oa[0]; o.y = oa[1]; o.z = oa[2]; o.w = oa[3];
            Ov[q] = o;
        }
    }
}

extern "C" void kernel_launch(void* const* d_in, const int* in_sizes, int n_in,
                              void* d_out, int out_size, void* d_ws, size_t ws_size,
                              hipStream_t stream) {
    const float* x     = (const float*)d_in[0];
    const float* rate  = (const float*)d_in[1];
    const float* phoff = (const float*)d_in[2];
    const float* W1    = (const float*)d_in[3];
    const float* b1    = (const float*)d_in[4];
    const float* W2    = (const float*)d_in[5];
    const float* b2    = (const float*)d_in[6];
    const float* amp   = (const float*)d_in[7];
    const float* bias_ = (const float*)d_in[8];
    const float* depth = (const float*)d_in[9];
    const float* g1    = (const float*)d_in[10];
    const float* pph   = (const float*)d_in[11];
    float* out = (float*)d_out;

    float* RECT = (float*)d_ws;                         // 30*TOTWG floats
    float* EST  = RECT + 30L * TOTWG;                   // 5*TOTWG floats
    unsigned int* FLG  = (unsigned int*)(EST + 5L * TOTWG);
    unsigned int* FLG2 = FLG + TOTWG;

    k_fused<<<dim3(TOTWG), dim3(WGT), 0, stream>>>(
        x, rate, phoff, W1, b1, W2, b2, amp, bias_, depth, g1, pph,
        out, RECT, EST, FLG, FLG2);
}